// Round 4
// baseline (3824.598 us; speedup 1.0000x reference)
//
#include <hip/hip_runtime.h>
#include <math.h>

// TransformerBlock1: b=4, DIM=192, h=256, w=192, HEADS=8, HID=768
#define SSP   49152
#define HDIM  256
#define WDIM  192
#define CDIM  192
#define NHEAD 8
#define CH    24
#define OC3   576
#define HIDF  768
#define NB    4
#define SCCH  24

typedef short bf16x8 __attribute__((ext_vector_type(8)));
typedef float f32x4  __attribute__((ext_vector_type(4)));

__device__ inline short f2bf(float f) {
  unsigned u = __float_as_uint(f);
  u += 0x7fffu + ((u >> 16) & 1u);
  return (short)(u >> 16);
}
__device__ inline float bf2f(short h) {
  return __uint_as_float(((unsigned)(unsigned short)h) << 16);
}

// ---------------- f32 -> bf16 bulk convert (weights) ----------------
__global__ __launch_bounds__(256) void cvt_bf16(const float* __restrict__ in,
                                                short* __restrict__ out, int n) {
  int i = blockIdx.x * 256 + threadIdx.x;
  if (i < n) out[i] = f2bf(in[i]);
}

// ---------------- zero small buffer ----------------
__global__ __launch_bounds__(256) void zero_f32(float* __restrict__ p, int n) {
  int i = blockIdx.x * 256 + threadIdx.x;
  if (i < n) p[i] = 0.f;
}

// ---------------- LN(channel) -> bf16 transposed [b][s][192] ----------------
__global__ __launch_bounds__(256) void ln_to_bf16T(const float* __restrict__ x,
                                                   const float* __restrict__ w,
                                                   const float* __restrict__ b,
                                                   short* __restrict__ yt) {
  int s = blockIdx.x * 256 + threadIdx.x;
  int bz = blockIdx.y;
  const float* xb = x + (size_t)bz * CDIM * SSP;
  float sum = 0.f, sq = 0.f;
  for (int c = 0; c < CDIM; ++c) {
    float v = xb[(size_t)c * SSP + s];
    sum += v; sq += v * v;
  }
  float mu = sum * (1.f / CDIM);
  float rstd = rsqrtf(sq * (1.f / CDIM) - mu * mu + 1e-5f);
  short* yp = yt + (size_t)bz * SSP * CDIM + (size_t)s * CDIM;
  for (int c8 = 0; c8 < CDIM / 8; ++c8) {
    bf16x8 v;
#pragma unroll
    for (int j = 0; j < 8; ++j) {
      int c = c8 * 8 + j;
      v[j] = f2bf((xb[(size_t)c * SSP + s] - mu) * rstd * w[c] + b[c]);
    }
    *(bf16x8*)(yp + c8 * 8) = v;
  }
}

// ---------------- LN(channel) -> bf16 natural [b][c][s] ----------------
__global__ __launch_bounds__(256) void ln_to_bf16N(const float* __restrict__ x,
                                                   const float* __restrict__ w,
                                                   const float* __restrict__ b,
                                                   short* __restrict__ y) {
  int s = blockIdx.x * 256 + threadIdx.x;
  int bz = blockIdx.y;
  const float* xb = x + (size_t)bz * CDIM * SSP;
  short* yb = y + (size_t)bz * CDIM * SSP;
  float sum = 0.f, sq = 0.f;
  for (int c = 0; c < CDIM; ++c) {
    float v = xb[(size_t)c * SSP + s];
    sum += v; sq += v * v;
  }
  float mu = sum * (1.f / CDIM);
  float rstd = rsqrtf(sq * (1.f / CDIM) - mu * mu + 1e-5f);
  for (int c = 0; c < CDIM; ++c) {
    float v = xb[(size_t)c * SSP + s];
    yb[(size_t)c * SSP + s] = f2bf((v - mu) * rstd * w[c] + b[c]);
  }
}

// ---------------- MFMA bf16 GEMM NT, batched over z ----------------
// C[m][n] = sum_k A[m][k]*B[n][k] (+resid) ; A shared across z, B/C/resid per z
template <int BM, int BN, int WM, int WN, bool RESID, bool OUT_BF16>
__global__ __launch_bounds__(256) void mfma_gemm(
    const short* __restrict__ A, const short* __restrict__ B,
    const float* __restrict__ resid, void* __restrict__ Cv,
    int M, int N, int K, long long strideB, long long strideC) {
  constexpr int BK = 32, PAD = 40;
  constexpr int WTM = BM / WM, WTN = BN / WN;
  constexpr int FM = WTM / 16, FN = WTN / 16;
  static_assert(WM * WN == 4 && BM % 64 == 0 && BN % 64 == 0, "cfg");
  __shared__ short As[BM * PAD];
  __shared__ short Bs[BN * PAD];
  const int tid = threadIdx.x;
  const int m0 = blockIdx.y * BM, n0 = blockIdx.x * BN;
  const long long z = blockIdx.z;
  const short* Bz = B + z * strideB;
  const int w = tid >> 6, lane = tid & 63;
  const int wm = w / WN, wn = w % WN;
  const int r16 = lane & 15, kg = lane >> 4;
  const int arow = tid >> 2, akc = tid & 3;

  f32x4 acc[FM][FN] = {};

  for (int k0 = 0; k0 < K; k0 += BK) {
#pragma unroll
    for (int i = 0; i < BM; i += 64) {
      bf16x8 v = *(const bf16x8*)(A + (size_t)(m0 + i + arow) * K + k0 + akc * 8);
      *(bf16x8*)(&As[(i + arow) * PAD + akc * 8]) = v;
    }
#pragma unroll
    for (int i = 0; i < BN; i += 64) {
      bf16x8 v = *(const bf16x8*)(Bz + (size_t)(n0 + i + arow) * K + k0 + akc * 8);
      *(bf16x8*)(&Bs[(i + arow) * PAD + akc * 8]) = v;
    }
    __syncthreads();
    bf16x8 af[FM], bfr[FN];
#pragma unroll
    for (int i = 0; i < FM; ++i)
      af[i] = *(bf16x8*)(&As[(wm * WTM + i * 16 + r16) * PAD + kg * 8]);
#pragma unroll
    for (int j = 0; j < FN; ++j)
      bfr[j] = *(bf16x8*)(&Bs[(wn * WTN + j * 16 + r16) * PAD + kg * 8]);
#pragma unroll
    for (int i = 0; i < FM; ++i)
#pragma unroll
      for (int j = 0; j < FN; ++j)
        acc[i][j] = __builtin_amdgcn_mfma_f32_16x16x32_bf16(af[i], bfr[j], acc[i][j], 0, 0, 0);
    __syncthreads();
  }

  float* Cf = (float*)Cv + z * strideC;
  short* Ch = (short*)Cv + z * strideC;
  const float* R = RESID ? resid + z * strideC : nullptr;
#pragma unroll
  for (int i = 0; i < FM; ++i) {
#pragma unroll
    for (int j = 0; j < FN; ++j) {
#pragma unroll
      for (int t = 0; t < 4; ++t) {
        int m = m0 + wm * WTM + i * 16 + kg * 4 + t;
        int n = n0 + wn * WTN + j * 16 + r16;
        float v = acc[i][j][t];
        size_t idx = (size_t)m * N + n;
        if (RESID) v += R[idx];
        if (OUT_BF16) Ch[idx] = f2bf(v); else Cf[idx] = v;
      }
    }
  }
}

// ---------------- 3x3 depthwise conv bf16->bf16 + q/k sumsq atomics ----------------
__global__ __launch_bounds__(256) void dwconv_rn(const short* __restrict__ in,
                                                 const float* __restrict__ w9,
                                                 short* __restrict__ outD,
                                                 float* __restrict__ rn) {
  size_t gid = (size_t)blockIdx.x * 256 + threadIdx.x;   // over NB*OC3*SSP
  int s = (int)(gid % SSP);
  int bo = (int)(gid / SSP);
  int o = bo % OC3, b = bo / OC3;
  int y = s / WDIM, x = s - y * WDIM;
  const short* ip = in + (size_t)bo * SSP;
  const float* wp = w9 + o * 9;
  float acc = 0.f;
#pragma unroll
  for (int dy = 0; dy < 3; ++dy) {
    int yy = y + dy - 1;
    if (yy < 0 || yy >= HDIM) continue;
#pragma unroll
    for (int dx = 0; dx < 3; ++dx) {
      int xx = x + dx - 1;
      if (xx < 0 || xx >= WDIM) continue;
      acc += wp[dy * 3 + dx] * bf2f(ip[yy * WDIM + xx]);
    }
  }
  outD[gid] = f2bf(acc);
  if (o < 2 * CDIM) {          // q,k rows: accumulate sum of squares
    float ss = acc * acc;
#pragma unroll
    for (int off = 32; off; off >>= 1) ss += __shfl_xor(ss, off);
    if ((threadIdx.x & 63) == 0) atomicAdd(&rn[b * 384 + o], ss);
  }
}

// ---------------- scores stage1 (bf16 q,k): partial raw dots ----------------
__global__ __launch_bounds__(256) void scores_stage1(const short* __restrict__ D,
                                                     float* __restrict__ partial) {
  int ch = blockIdx.x, h = blockIdx.y, b = blockIdx.z;
  __shared__ float qs[24][260];
  __shared__ float ks[24][260];
  int tid = threadIdx.x;
  int w = tid >> 6, lane = tid & 63;
  int c0 = w * 6;
  float acc[6] = {0.f, 0.f, 0.f, 0.f, 0.f, 0.f};
  const short* qb = D + ((size_t)b * OC3 + h * CH) * SSP;
  const short* kb = D + ((size_t)b * OC3 + CDIM + h * CH) * SSP;
  for (int it = 0; it < 8; ++it) {
    int s0 = ch * 2048 + it * 256;
#pragma unroll
    for (int p = 0; p < 3; ++p) {
      int u = p * 256 + tid;            // 0..767 over 24 rows x 32 chunks
      int row = u >> 5, col8 = u & 31;
      bf16x8 qv = *(const bf16x8*)(qb + (size_t)row * SSP + s0 + col8 * 8);
      bf16x8 kv = *(const bf16x8*)(kb + (size_t)row * SSP + s0 + col8 * 8);
#pragma unroll
      for (int j = 0; j < 8; ++j) {
        qs[row][col8 * 8 + j] = bf2f(qv[j]);
        ks[row][col8 * 8 + j] = bf2f(kv[j]);
      }
    }
    __syncthreads();
    if (lane < 24) {
      for (int s = 0; s < 256; s += 4) {
        float4 kv = *(float4*)&ks[lane][s];
#pragma unroll
        for (int i = 0; i < 6; ++i) {
          float4 qv = *(float4*)&qs[c0 + i][s];
          acc[i] += qv.x * kv.x + qv.y * kv.y + qv.z * kv.z + qv.w * kv.w;
        }
      }
    }
    __syncthreads();
  }
  if (lane < 24) {
    float* pb = partial + (size_t)b * (NHEAD * CH * CH * SCCH);
#pragma unroll
    for (int i = 0; i < 6; ++i)
      pb[(((size_t)h * CH + (c0 + i)) * CH + lane) * SCCH + ch] = acc[i];
  }
}

// ---------------- scores reduce + norms + temperature + softmax ----------------
__global__ void scores_reduce(const float* __restrict__ partial,
                              const float* __restrict__ rn,
                              const float* __restrict__ temp,
                              float* __restrict__ atn) {
  int c = blockIdx.x, h = blockIdx.y, b = blockIdx.z;
  int tid = threadIdx.x;   // 64
  __shared__ float row[24];
  const float* rb = rn + b * 384;
  if (tid < 24) {
    const float* p = partial + (size_t)b * (NHEAD * CH * CH * SCCH) +
                     (((size_t)h * CH + c) * CH + tid) * SCCH;
    float s = 0.f;
#pragma unroll
    for (int i = 0; i < SCCH; ++i) s += p[i];
    float rq = 1.f / fmaxf(sqrtf(rb[h * CH + c]), 1e-12f);
    float rk = 1.f / fmaxf(sqrtf(rb[CDIM + h * CH + tid]), 1e-12f);
    row[tid] = s * rq * rk * temp[h];
  }
  __syncthreads();
  if (tid < 24) {
    float mx = -1e30f;
    for (int d = 0; d < 24; ++d) mx = fmaxf(mx, row[d]);
    float sum = 0.f;
    for (int d = 0; d < 24; ++d) sum += expf(row[d] - mx);
    atn[((size_t)b * NHEAD + h) * 576 + c * CH + tid] = expf(row[tid] - mx) / sum;
  }
}

// ---------------- PV -> pvt bf16 [b][s][192] ----------------
__global__ __launch_bounds__(256) void attn_pv_bf16(const short* __restrict__ D,
                                                    const float* __restrict__ atn,
                                                    short* __restrict__ pvt) {
  int nb = blockIdx.x, h = blockIdx.y, b = blockIdx.z;
  __shared__ float aL[24][24];
  int tid = threadIdx.x;
  const float* ab = atn + ((size_t)b * NHEAD + h) * 576;
  for (int i = tid; i < 576; i += 256) aL[i / 24][i % 24] = ab[i];
  __syncthreads();
  int n = nb * 256 + tid;
  const short* vb = D + ((size_t)b * OC3 + 2 * CDIM + h * CH) * SSP + n;
  float vv[24];
#pragma unroll
  for (int d = 0; d < 24; ++d) vv[d] = bf2f(vb[(size_t)d * SSP]);
  short* ob = pvt + (size_t)b * SSP * CDIM + (size_t)n * CDIM + h * CH;
  bf16x8 o0, o1, o2;
#pragma unroll
  for (int cc = 0; cc < 24; ++cc) {
    float s = 0.f;
#pragma unroll
    for (int d = 0; d < 24; ++d) s += aL[cc][d] * vv[d];
    short bv = f2bf(s);
    if (cc < 8) o0[cc & 7] = bv; else if (cc < 16) o1[cc & 7] = bv; else o2[cc & 7] = bv;
  }
  *(bf16x8*)(ob) = o0;
  *(bf16x8*)(ob + 8) = o1;
  *(bf16x8*)(ob + 16) = o2;
}

// ---------------- fused MLP: out += gelu(y2 @ w1^T + b1) @ w2^T + b2 ----------------
// rows m: 196608 (= b*192*256 + c*256 + hh), row length 192 (w axis).
// Per block: 64 rows, full 192 out cols; hid in 12 chunks of 64; h1 chunk in LDS only.
__global__ __launch_bounds__(256) void mlp_fused(const short* __restrict__ y2,
                                                 const short* __restrict__ w1,
                                                 const short* __restrict__ w2,
                                                 const float* __restrict__ b1,
                                                 const float* __restrict__ b2,
                                                 float* __restrict__ out) {
  __shared__ short h1s[64][72];   // pad 72: 2-way bank pattern only
  const int tid = threadIdx.x;
  const int m0 = blockIdx.x * 64;
  const int w = tid >> 6, lane = tid & 63;
  const int r16 = lane & 15, kg = lane >> 4;
  const int mh = (w >> 1) * 32;       // m-half (both phases)
  const int nhA = (w & 1) * 32;       // phase A hid-half within chunk
  const int nbB = (w & 1) * 96;       // phase B out-col base

  f32x4 bacc[2][6] = {};

  for (int hc = 0; hc < 12; ++hc) {
    // phase A: h1c[64][64] = y2_tile @ w1_chunk^T, K=192 (direct-global frags)
    f32x4 pacc[2][2] = {};
#pragma unroll
    for (int ks = 0; ks < 6; ++ks) {
      bf16x8 af[2], bg[2];
#pragma unroll
      for (int i = 0; i < 2; ++i)
        af[i] = *(const bf16x8*)(y2 + (size_t)(m0 + mh + i * 16 + r16) * CDIM + ks * 32 + kg * 8);
#pragma unroll
      for (int j = 0; j < 2; ++j)
        bg[j] = *(const bf16x8*)(w1 + (size_t)(hc * 64 + nhA + j * 16 + r16) * CDIM + ks * 32 + kg * 8);
#pragma unroll
      for (int i = 0; i < 2; ++i)
#pragma unroll
        for (int j = 0; j < 2; ++j)
          pacc[i][j] = __builtin_amdgcn_mfma_f32_16x16x32_bf16(af[i], bg[j], pacc[i][j], 0, 0, 0);
    }
    // bias + exact gelu -> h1s (bf16)
#pragma unroll
    for (int i = 0; i < 2; ++i)
#pragma unroll
      for (int j = 0; j < 2; ++j)
#pragma unroll
        for (int t = 0; t < 4; ++t) {
          int mr = mh + i * 16 + kg * 4 + t;
          int nc = nhA + j * 16 + r16;
          float v = pacc[i][j][t] + b1[hc * 64 + nc];
          v = 0.5f * v * (1.f + erff(v * 0.70710678118654752f));
          h1s[mr][nc] = f2bf(v);
        }
    __syncthreads();
    // phase B: bacc += h1s @ w2_chunk^T, K=64 (w2 frags direct-global)
#pragma unroll
    for (int ks = 0; ks < 2; ++ks) {
      bf16x8 a2[2];
#pragma unroll
      for (int i = 0; i < 2; ++i)
        a2[i] = *(bf16x8*)(&h1s[mh + i * 16 + r16][ks * 32 + kg * 8]);
#pragma unroll
      for (int j = 0; j < 6; ++j) {
        bf16x8 b2g = *(const bf16x8*)(w2 + (size_t)(nbB + j * 16 + r16) * HIDF + hc * 64 + ks * 32 + kg * 8);
#pragma unroll
        for (int i = 0; i < 2; ++i)
          bacc[i][j] = __builtin_amdgcn_mfma_f32_16x16x32_bf16(a2[i], b2g, bacc[i][j], 0, 0, 0);
      }
    }
    __syncthreads();
  }
  // epilogue: + b2 + x1(resid, in out) -> out
#pragma unroll
  for (int i = 0; i < 2; ++i)
#pragma unroll
    for (int j = 0; j < 6; ++j)
#pragma unroll
      for (int t = 0; t < 4; ++t) {
        int m = m0 + mh + i * 16 + kg * 4 + t;
        int n = nbB + j * 16 + r16;
        size_t idx = (size_t)m * CDIM + n;
        out[idx] = bacc[i][j][t] + b2[n] + out[idx];
      }
}

extern "C" void kernel_launch(void* const* d_in, const int* in_sizes, int n_in,
                              void* d_out, int out_size, void* d_ws, size_t ws_size,
                              hipStream_t stream) {
  const float* x      = (const float*)d_in[0];
  const float* ln1_w  = (const float*)d_in[1];
  const float* ln1_b  = (const float*)d_in[2];
  const float* temp   = (const float*)d_in[3];
  const float* qkv_w  = (const float*)d_in[4];
  const float* dw_w   = (const float*)d_in[5];
  const float* proj_w = (const float*)d_in[6];
  const float* ln2_w  = (const float*)d_in[7];
  const float* ln2_b  = (const float*)d_in[8];
  const float* fc1_w  = (const float*)d_in[9];
  const float* fc1_b  = (const float*)d_in[10];
  const float* fc2_w  = (const float*)d_in[11];
  const float* fc2_b  = (const float*)d_in[12];
  float* out = (float*)d_out;

  char* base = (char*)d_ws;
  short* wq  = (short*)base;                     // 110592 sh
  short* wp  = wq + 110592;                      // 36864 sh
  short* w1  = wp + 36864;                       // 147456 sh
  short* w2  = w1 + 147456;                      // 147456 sh (ends @ 884736 B)
  float* rn  = (float*)(base + 884736);          // 4*384 f
  float* part= (float*)(base + 890880);          // 4*110592 f
  float* atn = (float*)(base + 2660352);         // 4*8*576 f
  short* Dv  = (short*)(base + 4194304);         // bf16 [4][576][SSP] = 216 MiB
  short* y1t = Dv;                               // bf16 [4][SSP][192] (dead before D written)
  short* T   = (short*)(base + 230686720);       // bf16 [4][576][SSP] = 216 MiB
  short* pvt = T;                                // reuse (T dead after dwconv)
  short* y2  = (short*)(base + 457179136);       // bf16 [4][192][SSP] = 72 MiB  (peak 508 MiB)

  // weights -> bf16 ; zero rn accumulators
  cvt_bf16<<<dim3(432), 256, 0, stream>>>(qkv_w, wq, 110592);
  cvt_bf16<<<dim3(144), 256, 0, stream>>>(proj_w, wp, 36864);
  cvt_bf16<<<dim3(576), 256, 0, stream>>>(fc1_w, w1, 147456);
  cvt_bf16<<<dim3(576), 256, 0, stream>>>(fc2_w, w2, 147456);
  zero_f32<<<dim3(6), 256, 0, stream>>>(rn, 1536);

  // 1. LN1 -> y1t bf16 [b][s][192]
  ln_to_bf16T<<<dim3(SSP / 256, NB), 256, 0, stream>>>(x, ln1_w, ln1_b, y1t);
  // 2. qkv GEMM (M=576,N=SSP,K=192, z=4) -> T bf16
  mfma_gemm<64, 256, 1, 4, false, true><<<dim3(SSP / 256, OC3 / 64, NB), 256, 0, stream>>>(
      wq, y1t, nullptr, T, OC3, SSP, CDIM, (long long)SSP * CDIM, (long long)OC3 * SSP);
  // 3. depthwise 3x3 + q/k sumsq -> Dv bf16, rn
  dwconv_rn<<<dim3((unsigned)((size_t)NB * OC3 * SSP / 256)), 256, 0, stream>>>(T, dw_w, Dv, rn);
  // 4. scores: partial dots, then reduce+norm+softmax
  scores_stage1<<<dim3(SCCH, NHEAD, NB), 256, 0, stream>>>(Dv, part);
  scores_reduce<<<dim3(CH, NHEAD, NB), 64, 0, stream>>>(part, rn, temp, atn);
  // 5. PV -> pvt bf16 [b][s][192]
  attn_pv_bf16<<<dim3(SSP / 256, NHEAD, NB), 256, 0, stream>>>(Dv, atn, pvt);
  // 6. x1 = proj @ pv + x -> out (fp32)
  mfma_gemm<64, 256, 1, 4, true, false><<<dim3(SSP / 256, CDIM / 64, NB), 256, 0, stream>>>(
      wp, pvt, x, out, CDIM, SSP, CDIM, (long long)SSP * CDIM, (long long)CDIM * SSP);
  // 7. LN2 -> y2 bf16 [b][c][s]
  ln_to_bf16N<<<dim3(SSP / 256, NB), 256, 0, stream>>>(out, ln2_w, ln2_b, y2);
  // 8. fused MLP: out += gelu(y2@w1^T+b1)@w2^T + b2   (196608 rows / 64 per block)
  mlp_fused<<<dim3(196608 / 64), 256, 0, stream>>>(y2, w1, w2, fc1_b, fc2_b, out);
}

// Round 5
// 1215.967 us; speedup vs baseline: 3.1453x; 3.1453x over previous
//
#include <hip/hip_runtime.h>
#include <math.h>

// TransformerBlock1: b=4, DIM=192, h=256, w=192, HEADS=8, HID=768
#define SSP   49152
#define HDIM  256
#define WDIM  192
#define CDIM  192
#define NHEAD 8
#define CH    24
#define OC3   576
#define HIDF  768
#define NB    4
#define SCCH  24

typedef short bf16x8 __attribute__((ext_vector_type(8)));
typedef float f32x4  __attribute__((ext_vector_type(4)));

__device__ inline short f2bf(float f) {
  unsigned u = __float_as_uint(f);
  u += 0x7fffu + ((u >> 16) & 1u);
  return (short)(u >> 16);
}
__device__ inline float bf2f(short h) {
  return __uint_as_float(((unsigned)(unsigned short)h) << 16);
}

// ---------------- f32 -> bf16 bulk convert (weights) ----------------
__global__ __launch_bounds__(256) void cvt_bf16(const float* __restrict__ in,
                                                short* __restrict__ out, int n) {
  int i = blockIdx.x * 256 + threadIdx.x;
  if (i < n) out[i] = f2bf(in[i]);
}

// ---------------- LN(channel) -> bf16 transposed [b][s][192] ----------------
__global__ __launch_bounds__(256) void ln_to_bf16T(const float* __restrict__ x,
                                                   const float* __restrict__ w,
                                                   const float* __restrict__ b,
                                                   short* __restrict__ yt) {
  int s = blockIdx.x * 256 + threadIdx.x;
  int bz = blockIdx.y;
  const float* xb = x + (size_t)bz * CDIM * SSP;
  float sum = 0.f, sq = 0.f;
  for (int c = 0; c < CDIM; ++c) {
    float v = xb[(size_t)c * SSP + s];
    sum += v; sq += v * v;
  }
  float mu = sum * (1.f / CDIM);
  float rstd = rsqrtf(sq * (1.f / CDIM) - mu * mu + 1e-5f);
  short* yp = yt + (size_t)bz * SSP * CDIM + (size_t)s * CDIM;
  for (int c8 = 0; c8 < CDIM / 8; ++c8) {
    bf16x8 v;
#pragma unroll
    for (int j = 0; j < 8; ++j) {
      int c = c8 * 8 + j;
      v[j] = f2bf((xb[(size_t)c * SSP + s] - mu) * rstd * w[c] + b[c]);
    }
    *(bf16x8*)(yp + c8 * 8) = v;
  }
}

// ---------------- LN(channel) -> bf16 natural [b][c][s] ----------------
__global__ __launch_bounds__(256) void ln_to_bf16N(const float* __restrict__ x,
                                                   const float* __restrict__ w,
                                                   const float* __restrict__ b,
                                                   short* __restrict__ y) {
  int s = blockIdx.x * 256 + threadIdx.x;
  int bz = blockIdx.y;
  const float* xb = x + (size_t)bz * CDIM * SSP;
  short* yb = y + (size_t)bz * CDIM * SSP;
  float sum = 0.f, sq = 0.f;
  for (int c = 0; c < CDIM; ++c) {
    float v = xb[(size_t)c * SSP + s];
    sum += v; sq += v * v;
  }
  float mu = sum * (1.f / CDIM);
  float rstd = rsqrtf(sq * (1.f / CDIM) - mu * mu + 1e-5f);
  for (int c = 0; c < CDIM; ++c) {
    float v = xb[(size_t)c * SSP + s];
    yb[(size_t)c * SSP + s] = f2bf((v - mu) * rstd * w[c] + b[c]);
  }
}

// ---------------- MFMA bf16 GEMM NT, batched over z ----------------
template <int BM, int BN, int WM, int WN, bool RESID, bool OUT_BF16>
__global__ __launch_bounds__(256) void mfma_gemm(
    const short* __restrict__ A, const short* __restrict__ B,
    const float* __restrict__ resid, void* __restrict__ Cv,
    int M, int N, int K, long long strideB, long long strideC) {
  constexpr int BK = 32, PAD = 40;
  constexpr int WTM = BM / WM, WTN = BN / WN;
  constexpr int FM = WTM / 16, FN = WTN / 16;
  static_assert(WM * WN == 4 && BM % 64 == 0 && BN % 64 == 0, "cfg");
  __shared__ short As[BM * PAD];
  __shared__ short Bs[BN * PAD];
  const int tid = threadIdx.x;
  const int m0 = blockIdx.y * BM, n0 = blockIdx.x * BN;
  const long long z = blockIdx.z;
  const short* Bz = B + z * strideB;
  const int w = tid >> 6, lane = tid & 63;
  const int wm = w / WN, wn = w % WN;
  const int r16 = lane & 15, kg = lane >> 4;
  const int arow = tid >> 2, akc = tid & 3;

  f32x4 acc[FM][FN] = {};

  for (int k0 = 0; k0 < K; k0 += BK) {
#pragma unroll
    for (int i = 0; i < BM; i += 64) {
      bf16x8 v = *(const bf16x8*)(A + (size_t)(m0 + i + arow) * K + k0 + akc * 8);
      *(bf16x8*)(&As[(i + arow) * PAD + akc * 8]) = v;
    }
#pragma unroll
    for (int i = 0; i < BN; i += 64) {
      bf16x8 v = *(const bf16x8*)(Bz + (size_t)(n0 + i + arow) * K + k0 + akc * 8);
      *(bf16x8*)(&Bs[(i + arow) * PAD + akc * 8]) = v;
    }
    __syncthreads();
    bf16x8 af[FM], bfr[FN];
#pragma unroll
    for (int i = 0; i < FM; ++i)
      af[i] = *(bf16x8*)(&As[(wm * WTM + i * 16 + r16) * PAD + kg * 8]);
#pragma unroll
    for (int j = 0; j < FN; ++j)
      bfr[j] = *(bf16x8*)(&Bs[(wn * WTN + j * 16 + r16) * PAD + kg * 8]);
#pragma unroll
    for (int i = 0; i < FM; ++i)
#pragma unroll
      for (int j = 0; j < FN; ++j)
        acc[i][j] = __builtin_amdgcn_mfma_f32_16x16x32_bf16(af[i], bfr[j], acc[i][j], 0, 0, 0);
    __syncthreads();
  }

  float* Cf = (float*)Cv + z * strideC;
  short* Ch = (short*)Cv + z * strideC;
  const float* R = RESID ? resid + z * strideC : nullptr;
#pragma unroll
  for (int i = 0; i < FM; ++i) {
#pragma unroll
    for (int j = 0; j < FN; ++j) {
#pragma unroll
      for (int t = 0; t < 4; ++t) {
        int m = m0 + wm * WTM + i * 16 + kg * 4 + t;
        int n = n0 + wn * WTN + j * 16 + r16;
        float v = acc[i][j][t];
        size_t idx = (size_t)m * N + n;
        if (RESID) v += R[idx];
        if (OUT_BF16) Ch[idx] = f2bf(v); else Cf[idx] = v;
      }
    }
  }
}

// ---------------- 3x3 depthwise conv, LDS-tiled, bf16->bf16, no atomics ----------------
// block = one channel (b*OC3+o) x one 32-row slab; tile has 1-row halos and
// zero-padded cols; all index math int32; vec8 loads/stores.
__global__ __launch_bounds__(256) void dwconv_tile(const short* __restrict__ in,
                                                   const float* __restrict__ w9,
                                                   short* __restrict__ out) {
  __shared__ short tile[34][208];   // rows y0-1..y0+32, cols: x-1 at 7, x=0..191 at 8..199, x=192 at 200
  const int tid = threadIdx.x;
  const int ch = blockIdx.x >> 3;        // b*OC3 + o
  const int slab = blockIdx.x & 7;
  const int o = ch % OC3;
  const int y0 = slab * 32;
  float wr[9];
#pragma unroll
  for (int i = 0; i < 9; ++i) wr[i] = w9[o * 9 + i];
  const short* ip = in + (size_t)ch * SSP;

  if (tid < 34) { tile[tid][7] = 0; tile[tid][200] = 0; }
#pragma unroll
  for (int i = 0; i < 4; ++i) {
    int idx = i * 256 + tid;
    if (idx < 816) {                      // 34 rows x 24 vec8 chunks
      int row = idx / 24, cx = idx - row * 24;
      int gy = y0 + row - 1;
      bf16x8 v = {};
      if (gy >= 0 && gy < HDIM) v = *(const bf16x8*)(ip + gy * WDIM + cx * 8);
      *(bf16x8*)(&tile[row][8 + cx * 8]) = v;
    }
  }
  __syncthreads();

  short* op = out + (size_t)ch * SSP;
#pragma unroll
  for (int g = 0; g < 3; ++g) {
    int G = g * 256 + tid;                // < 768 = 32 rows x 24 chunks
    int r = G / 24, cx = G - (G / 24) * 24;
    int cb = cx * 8 + 7;
    float a[10], b[10], c[10];
#pragma unroll
    for (int d = 0; d < 10; ++d) {
      a[d] = bf2f(tile[r][cb + d]);
      b[d] = bf2f(tile[r + 1][cb + d]);
      c[d] = bf2f(tile[r + 2][cb + d]);
    }
    bf16x8 ov;
#pragma unroll
    for (int j = 0; j < 8; ++j) {
      float acc = wr[0] * a[j] + wr[1] * a[j + 1] + wr[2] * a[j + 2]
                + wr[3] * b[j] + wr[4] * b[j + 1] + wr[5] * b[j + 2]
                + wr[6] * c[j] + wr[7] * c[j + 1] + wr[8] * c[j + 2];
      ov[j] = f2bf(acc);
    }
    *(bf16x8*)(op + (y0 + r) * WDIM + cx * 8) = ov;
  }
}

// ---------------- scores stage1: partial dots + per-row sumsq chunks ----------------
__global__ __launch_bounds__(256) void scores_stage1(const short* __restrict__ D,
                                                     float* __restrict__ pdot,
                                                     float* __restrict__ qss,
                                                     float* __restrict__ kss) {
  int ch = blockIdx.x, h = blockIdx.y, b = blockIdx.z;
  __shared__ float qs[24][260];
  __shared__ float ks[24][260];
  int tid = threadIdx.x;
  int w = tid >> 6, lane = tid & 63;
  int c0 = w * 6;
  float acc[6] = {0.f, 0.f, 0.f, 0.f, 0.f, 0.f};
  float ssacc = 0.f;
  const short* qb = D + ((size_t)b * OC3 + h * CH) * SSP;
  const short* kb = D + ((size_t)b * OC3 + CDIM + h * CH) * SSP;
  for (int it = 0; it < 8; ++it) {
    int s0 = ch * 2048 + it * 256;
#pragma unroll
    for (int p = 0; p < 3; ++p) {
      int u = p * 256 + tid;            // 0..767 over 24 rows x 32 chunks
      int row = u >> 5, col8 = u & 31;
      bf16x8 qv = *(const bf16x8*)(qb + (size_t)row * SSP + s0 + col8 * 8);
      bf16x8 kv = *(const bf16x8*)(kb + (size_t)row * SSP + s0 + col8 * 8);
#pragma unroll
      for (int j = 0; j < 8; ++j) {
        qs[row][col8 * 8 + j] = bf2f(qv[j]);
        ks[row][col8 * 8 + j] = bf2f(kv[j]);
      }
    }
    __syncthreads();
    if (w < 2 && lane < 24) {           // sumsq: wave0 -> q, wave1 -> k
      const float (*src)[260] = (w == 0) ? qs : ks;
      for (int s = 0; s < 256; s += 4) {
        float4 v = *(const float4*)&src[lane][s];
        ssacc += v.x * v.x + v.y * v.y + v.z * v.z + v.w * v.w;
      }
    }
    if (lane < 24) {
      for (int s = 0; s < 256; s += 4) {
        float4 kv = *(float4*)&ks[lane][s];
#pragma unroll
        for (int i = 0; i < 6; ++i) {
          float4 qv = *(float4*)&qs[c0 + i][s];
          acc[i] += qv.x * kv.x + qv.y * kv.y + qv.z * kv.z + qv.w * kv.w;
        }
      }
    }
    __syncthreads();
  }
  if (lane < 24) {
    float* pb = pdot + (size_t)b * (NHEAD * CH * CH * SCCH);
#pragma unroll
    for (int i = 0; i < 6; ++i)
      pb[(((size_t)h * CH + (c0 + i)) * CH + lane) * SCCH + ch] = acc[i];
    if (w == 0) qss[(((size_t)b * NHEAD + h) * CH + lane) * SCCH + ch] = ssacc;
    if (w == 1) kss[(((size_t)b * NHEAD + h) * CH + lane) * SCCH + ch] = ssacc;
  }
}

// ---------------- scores reduce + norms + temperature + softmax ----------------
__global__ void scores_reduce(const float* __restrict__ pdot,
                              const float* __restrict__ qss,
                              const float* __restrict__ kss,
                              const float* __restrict__ temp,
                              float* __restrict__ atn) {
  int c = blockIdx.x, h = blockIdx.y, b = blockIdx.z;
  int tid = threadIdx.x;   // 64
  __shared__ float row[24];
  if (tid < 24) {
    const float* p = pdot + (size_t)b * (NHEAD * CH * CH * SCCH) +
                     (((size_t)h * CH + c) * CH + tid) * SCCH;
    float s = 0.f;
#pragma unroll
    for (int i = 0; i < SCCH; ++i) s += p[i];
    const float* pq = qss + (((size_t)b * NHEAD + h) * CH + c) * SCCH;
    const float* pk = kss + (((size_t)b * NHEAD + h) * CH + tid) * SCCH;
    float sq = 0.f, sk = 0.f;
#pragma unroll
    for (int i = 0; i < SCCH; ++i) { sq += pq[i]; sk += pk[i]; }
    float rq = 1.f / fmaxf(sqrtf(sq), 1e-12f);
    float rk = 1.f / fmaxf(sqrtf(sk), 1e-12f);
    row[tid] = s * rq * rk * temp[h];
  }
  __syncthreads();
  if (tid < 24) {
    float mx = -1e30f;
    for (int d = 0; d < 24; ++d) mx = fmaxf(mx, row[d]);
    float sum = 0.f;
    for (int d = 0; d < 24; ++d) sum += expf(row[d] - mx);
    atn[((size_t)b * NHEAD + h) * 576 + c * CH + tid] = expf(row[tid] - mx) / sum;
  }
}

// ---------------- PV -> pvt bf16 [b][s][192] ----------------
__global__ __launch_bounds__(256) void attn_pv_bf16(const short* __restrict__ D,
                                                    const float* __restrict__ atn,
                                                    short* __restrict__ pvt) {
  int nb = blockIdx.x, h = blockIdx.y, b = blockIdx.z;
  __shared__ float aL[24][24];
  int tid = threadIdx.x;
  const float* ab = atn + ((size_t)b * NHEAD + h) * 576;
  for (int i = tid; i < 576; i += 256) aL[i / 24][i % 24] = ab[i];
  __syncthreads();
  int n = nb * 256 + tid;
  const short* vb = D + ((size_t)b * OC3 + 2 * CDIM + h * CH) * SSP + n;
  float vv[24];
#pragma unroll
  for (int d = 0; d < 24; ++d) vv[d] = bf2f(vb[(size_t)d * SSP]);
  short* ob = pvt + (size_t)b * SSP * CDIM + (size_t)n * CDIM + h * CH;
  bf16x8 o0, o1, o2;
#pragma unroll
  for (int cc = 0; cc < 24; ++cc) {
    float s = 0.f;
#pragma unroll
    for (int d = 0; d < 24; ++d) s += aL[cc][d] * vv[d];
    short bv = f2bf(s);
    if (cc < 8) o0[cc & 7] = bv; else if (cc < 16) o1[cc & 7] = bv; else o2[cc & 7] = bv;
  }
  *(bf16x8*)(ob) = o0;
  *(bf16x8*)(ob + 8) = o1;
  *(bf16x8*)(ob + 16) = o2;
}

// ---------------- fused MLP: out += gelu(y2 @ w1^T + b1) @ w2^T + b2 ----------------
__global__ __launch_bounds__(256) void mlp_fused(const short* __restrict__ y2,
                                                 const short* __restrict__ w1,
                                                 const short* __restrict__ w2,
                                                 const float* __restrict__ b1,
                                                 const float* __restrict__ b2,
                                                 float* __restrict__ out) {
  __shared__ short h1s[64][72];
  const int tid = threadIdx.x;
  const int m0 = blockIdx.x * 64;
  const int w = tid >> 6, lane = tid & 63;
  const int r16 = lane & 15, kg = lane >> 4;
  const int mh = (w >> 1) * 32;
  const int nhA = (w & 1) * 32;
  const int nbB = (w & 1) * 96;

  f32x4 bacc[2][6] = {};

  for (int hc = 0; hc < 12; ++hc) {
    f32x4 pacc[2][2] = {};
#pragma unroll
    for (int ks = 0; ks < 6; ++ks) {
      bf16x8 af[2], bg[2];
#pragma unroll
      for (int i = 0; i < 2; ++i)
        af[i] = *(const bf16x8*)(y2 + (size_t)(m0 + mh + i * 16 + r16) * CDIM + ks * 32 + kg * 8);
#pragma unroll
      for (int j = 0; j < 2; ++j)
        bg[j] = *(const bf16x8*)(w1 + (size_t)(hc * 64 + nhA + j * 16 + r16) * CDIM + ks * 32 + kg * 8);
#pragma unroll
      for (int i = 0; i < 2; ++i)
#pragma unroll
        for (int j = 0; j < 2; ++j)
          pacc[i][j] = __builtin_amdgcn_mfma_f32_16x16x32_bf16(af[i], bg[j], pacc[i][j], 0, 0, 0);
    }
#pragma unroll
    for (int i = 0; i < 2; ++i)
#pragma unroll
      for (int j = 0; j < 2; ++j)
#pragma unroll
        for (int t = 0; t < 4; ++t) {
          int mr = mh + i * 16 + kg * 4 + t;
          int nc = nhA + j * 16 + r16;
          float v = pacc[i][j][t] + b1[hc * 64 + nc];
          v = 0.5f * v * (1.f + erff(v * 0.70710678118654752f));
          h1s[mr][nc] = f2bf(v);
        }
    __syncthreads();
#pragma unroll
    for (int ks = 0; ks < 2; ++ks) {
      bf16x8 a2[2];
#pragma unroll
      for (int i = 0; i < 2; ++i)
        a2[i] = *(bf16x8*)(&h1s[mh + i * 16 + r16][ks * 32 + kg * 8]);
#pragma unroll
      for (int j = 0; j < 6; ++j) {
        bf16x8 b2g = *(const bf16x8*)(w2 + (size_t)(nbB + j * 16 + r16) * HIDF + hc * 64 + ks * 32 + kg * 8);
#pragma unroll
        for (int i = 0; i < 2; ++i)
          bacc[i][j] = __builtin_amdgcn_mfma_f32_16x16x32_bf16(a2[i], b2g, bacc[i][j], 0, 0, 0);
      }
    }
    __syncthreads();
  }
#pragma unroll
  for (int i = 0; i < 2; ++i)
#pragma unroll
    for (int j = 0; j < 6; ++j)
#pragma unroll
      for (int t = 0; t < 4; ++t) {
        int m = m0 + mh + i * 16 + kg * 4 + t;
        int n = nbB + j * 16 + r16;
        size_t idx = (size_t)m * CDIM + n;
        out[idx] = bacc[i][j][t] + b2[n] + out[idx];
      }
}

extern "C" void kernel_launch(void* const* d_in, const int* in_sizes, int n_in,
                              void* d_out, int out_size, void* d_ws, size_t ws_size,
                              hipStream_t stream) {
  const float* x      = (const float*)d_in[0];
  const float* ln1_w  = (const float*)d_in[1];
  const float* ln1_b  = (const float*)d_in[2];
  const float* temp   = (const float*)d_in[3];
  const float* qkv_w  = (const float*)d_in[4];
  const float* dw_w   = (const float*)d_in[5];
  const float* proj_w = (const float*)d_in[6];
  const float* ln2_w  = (const float*)d_in[7];
  const float* ln2_b  = (const float*)d_in[8];
  const float* fc1_w  = (const float*)d_in[9];
  const float* fc1_b  = (const float*)d_in[10];
  const float* fc2_w  = (const float*)d_in[11];
  const float* fc2_b  = (const float*)d_in[12];
  float* out = (float*)d_out;

  char* base = (char*)d_ws;
  short* wq  = (short*)base;                     // 110592 sh
  short* wp  = wq + 110592;                      // 36864 sh
  short* w1  = wp + 36864;                       // 147456 sh
  short* w2  = w1 + 147456;                      // 147456 sh (ends @ 884736 B)
  float* pdot= (float*)(base + 890880);          // 4*110592 f -> ends 2,660,352
  float* qss = (float*)(base + 2660352);         // 4*8*24*24 f -> ends 2,734,080
  float* kss = (float*)(base + 2734080);         // -> ends 2,807,808
  float* atn = (float*)(base + 2807808);         // 4*8*576 f -> ends 2,881,536
  short* Dv  = (short*)(base + 4194304);         // bf16 [4][576][SSP] = 216 MiB
  short* y1t = Dv;                               // bf16 [4][SSP][192] (dead before D written)
  short* T   = (short*)(base + 230686720);       // bf16 [4][576][SSP] = 216 MiB
  short* pvt = T;                                // reuse (T dead after dwconv)
  short* y2  = (short*)(base + 457179136);       // bf16 [4][192][SSP] = 72 MiB (peak 508 MiB)

  // weights -> bf16
  cvt_bf16<<<dim3(432), 256, 0, stream>>>(qkv_w, wq, 110592);
  cvt_bf16<<<dim3(144), 256, 0, stream>>>(proj_w, wp, 36864);
  cvt_bf16<<<dim3(576), 256, 0, stream>>>(fc1_w, w1, 147456);
  cvt_bf16<<<dim3(576), 256, 0, stream>>>(fc2_w, w2, 147456);

  // 1. LN1 -> y1t bf16 [b][s][192]
  ln_to_bf16T<<<dim3(SSP / 256, NB), 256, 0, stream>>>(x, ln1_w, ln1_b, y1t);
  // 2. qkv GEMM (M=576,N=SSP,K=192, z=4) -> T bf16
  mfma_gemm<64, 256, 1, 4, false, true><<<dim3(SSP / 256, OC3 / 64, NB), 256, 0, stream>>>(
      wq, y1t, nullptr, T, OC3, SSP, CDIM, (long long)SSP * CDIM, (long long)OC3 * SSP);
  // 3. depthwise 3x3 tiled -> Dv bf16 (no atomics)
  dwconv_tile<<<dim3(NB * OC3 * 8), 256, 0, stream>>>(T, dw_w, Dv);
  // 4. scores: partial dots + sumsq, then reduce+norm+softmax
  scores_stage1<<<dim3(SCCH, NHEAD, NB), 256, 0, stream>>>(Dv, pdot, qss, kss);
  scores_reduce<<<dim3(CH, NHEAD, NB), 64, 0, stream>>>(pdot, qss, kss, temp, atn);
  // 5. PV -> pvt bf16 [b][s][192]
  attn_pv_bf16<<<dim3(SSP / 256, NHEAD, NB), 256, 0, stream>>>(Dv, atn, pvt);
  // 6. x1 = proj @ pv + x -> out (fp32)
  mfma_gemm<64, 256, 1, 4, true, false><<<dim3(SSP / 256, CDIM / 64, NB), 256, 0, stream>>>(
      wp, pvt, x, out, CDIM, SSP, CDIM, (long long)SSP * CDIM, (long long)CDIM * SSP);
  // 7. LN2 -> y2 bf16 [b][c][s]
  ln_to_bf16N<<<dim3(SSP / 256, NB), 256, 0, stream>>>(out, ln2_w, ln2_b, y2);
  // 8. fused MLP: out += gelu(y2@w1^T+b1)@w2^T + b2
  mlp_fused<<<dim3(196608 / 64), 256, 0, stream>>>(y2, w1, w2, fc1_b, fc2_b, out);
}

// Round 7
// 1016.610 us; speedup vs baseline: 3.7621x; 1.1961x over previous
//
#include <hip/hip_runtime.h>
#include <math.h>

// TransformerBlock1: b=4, DIM=192, h=256, w=192, HEADS=8, HID=768
#define SSP   49152
#define HDIM  256
#define WDIM  192
#define CDIM  192
#define NHEAD 8
#define CH    24
#define OC3   576
#define HIDF  768
#define NB    4
#define SCCH  24

typedef short bf16x8 __attribute__((ext_vector_type(8)));
typedef float f32x4  __attribute__((ext_vector_type(4)));

__device__ inline short f2bf(float f) {
  unsigned u = __float_as_uint(f);
  u += 0x7fffu + ((u >> 16) & 1u);
  return (short)(u >> 16);
}
__device__ inline float bf2f(short h) {
  return __uint_as_float(((unsigned)(unsigned short)h) << 16);
}

// ---------------- f32 -> bf16 bulk convert (weights) ----------------
__global__ __launch_bounds__(256) void cvt_bf16(const float* __restrict__ in,
                                                short* __restrict__ out, int n) {
  int i = blockIdx.x * 256 + threadIdx.x;
  if (i < n) out[i] = f2bf(in[i]);
}

// ---------------- LN(channel) -> bf16 transposed [b][s][192] ----------------
__global__ __launch_bounds__(256) void ln_to_bf16T(const float* __restrict__ x,
                                                   const float* __restrict__ w,
                                                   const float* __restrict__ b,
                                                   short* __restrict__ yt) {
  int s = blockIdx.x * 256 + threadIdx.x;
  int bz = blockIdx.y;
  const float* xb = x + (size_t)bz * CDIM * SSP;
  float sum = 0.f, sq = 0.f;
  for (int c = 0; c < CDIM; ++c) {
    float v = xb[(size_t)c * SSP + s];
    sum += v; sq += v * v;
  }
  float mu = sum * (1.f / CDIM);
  float rstd = rsqrtf(sq * (1.f / CDIM) - mu * mu + 1e-5f);
  short* yp = yt + (size_t)bz * SSP * CDIM + (size_t)s * CDIM;
  for (int c8 = 0; c8 < CDIM / 8; ++c8) {
    bf16x8 v;
#pragma unroll
    for (int j = 0; j < 8; ++j) {
      int c = c8 * 8 + j;
      v[j] = f2bf((xb[(size_t)c * SSP + s] - mu) * rstd * w[c] + b[c]);
    }
    *(bf16x8*)(yp + c8 * 8) = v;
  }
}

// ---------------- LN(channel) -> bf16 natural [b][c][s] ----------------
__global__ __launch_bounds__(256) void ln_to_bf16N(const float* __restrict__ x,
                                                   const float* __restrict__ w,
                                                   const float* __restrict__ b,
                                                   short* __restrict__ y) {
  int s = blockIdx.x * 256 + threadIdx.x;
  int bz = blockIdx.y;
  const float* xb = x + (size_t)bz * CDIM * SSP;
  short* yb = y + (size_t)bz * CDIM * SSP;
  float sum = 0.f, sq = 0.f;
  for (int c = 0; c < CDIM; ++c) {
    float v = xb[(size_t)c * SSP + s];
    sum += v; sq += v * v;
  }
  float mu = sum * (1.f / CDIM);
  float rstd = rsqrtf(sq * (1.f / CDIM) - mu * mu + 1e-5f);
  for (int c = 0; c < CDIM; ++c) {
    float v = xb[(size_t)c * SSP + s];
    yb[(size_t)c * SSP + s] = f2bf((v - mu) * rstd * w[c] + b[c]);
  }
}

// ---------------- MFMA bf16 GEMM NT, batched over z ----------------
template <int BM, int BN, int WM, int WN, bool RESID, bool OUT_BF16>
__global__ __launch_bounds__(256) void mfma_gemm(
    const short* __restrict__ A, const short* __restrict__ B,
    const float* __restrict__ resid, void* __restrict__ Cv,
    int M, int N, int K, long long strideB, long long strideC) {
  constexpr int BK = 32, PAD = 40;
  constexpr int WTM = BM / WM, WTN = BN / WN;
  constexpr int FM = WTM / 16, FN = WTN / 16;
  static_assert(WM * WN == 4 && BM % 64 == 0 && BN % 64 == 0, "cfg");
  __shared__ short As[BM * PAD];
  __shared__ short Bs[BN * PAD];
  const int tid = threadIdx.x;
  const int m0 = blockIdx.y * BM, n0 = blockIdx.x * BN;
  const long long z = blockIdx.z;
  const short* Bz = B + z * strideB;
  const int w = tid >> 6, lane = tid & 63;
  const int wm = w / WN, wn = w % WN;
  const int r16 = lane & 15, kg = lane >> 4;
  const int arow = tid >> 2, akc = tid & 3;

  f32x4 acc[FM][FN] = {};

  for (int k0 = 0; k0 < K; k0 += BK) {
#pragma unroll
    for (int i = 0; i < BM; i += 64) {
      bf16x8 v = *(const bf16x8*)(A + (size_t)(m0 + i + arow) * K + k0 + akc * 8);
      *(bf16x8*)(&As[(i + arow) * PAD + akc * 8]) = v;
    }
#pragma unroll
    for (int i = 0; i < BN; i += 64) {
      bf16x8 v = *(const bf16x8*)(Bz + (size_t)(n0 + i + arow) * K + k0 + akc * 8);
      *(bf16x8*)(&Bs[(i + arow) * PAD + akc * 8]) = v;
    }
    __syncthreads();
    bf16x8 af[FM], bfr[FN];
#pragma unroll
    for (int i = 0; i < FM; ++i)
      af[i] = *(bf16x8*)(&As[(wm * WTM + i * 16 + r16) * PAD + kg * 8]);
#pragma unroll
    for (int j = 0; j < FN; ++j)
      bfr[j] = *(bf16x8*)(&Bs[(wn * WTN + j * 16 + r16) * PAD + kg * 8]);
#pragma unroll
    for (int i = 0; i < FM; ++i)
#pragma unroll
      for (int j = 0; j < FN; ++j)
        acc[i][j] = __builtin_amdgcn_mfma_f32_16x16x32_bf16(af[i], bfr[j], acc[i][j], 0, 0, 0);
    __syncthreads();
  }

  float* Cf = (float*)Cv + z * strideC;
  short* Ch = (short*)Cv + z * strideC;
  const float* R = RESID ? resid + z * strideC : nullptr;
#pragma unroll
  for (int i = 0; i < FM; ++i) {
#pragma unroll
    for (int j = 0; j < FN; ++j) {
#pragma unroll
      for (int t = 0; t < 4; ++t) {
        int m = m0 + wm * WTM + i * 16 + kg * 4 + t;
        int n = n0 + wn * WTN + j * 16 + r16;
        float v = acc[i][j][t];
        size_t idx = (size_t)m * N + n;
        if (RESID) v += R[idx];
        if (OUT_BF16) Ch[idx] = f2bf(v); else Cf[idx] = v;
      }
    }
  }
}

// ---------------- 3x3 depthwise conv, LDS-tiled, bf16->bf16 ----------------
__global__ __launch_bounds__(256) void dwconv_tile(const short* __restrict__ in,
                                                   const float* __restrict__ w9,
                                                   short* __restrict__ out) {
  __shared__ short tile[34][208];
  const int tid = threadIdx.x;
  const int ch = blockIdx.x >> 3;
  const int slab = blockIdx.x & 7;
  const int o = ch % OC3;
  const int y0 = slab * 32;
  float wr[9];
#pragma unroll
  for (int i = 0; i < 9; ++i) wr[i] = w9[o * 9 + i];
  const short* ip = in + (size_t)ch * SSP;

  if (tid < 34) { tile[tid][7] = 0; tile[tid][200] = 0; }
#pragma unroll
  for (int i = 0; i < 4; ++i) {
    int idx = i * 256 + tid;
    if (idx < 816) {
      int row = idx / 24, cx = idx - row * 24;
      int gy = y0 + row - 1;
      bf16x8 v = {};
      if (gy >= 0 && gy < HDIM) v = *(const bf16x8*)(ip + gy * WDIM + cx * 8);
      *(bf16x8*)(&tile[row][8 + cx * 8]) = v;
    }
  }
  __syncthreads();

  short* op = out + (size_t)ch * SSP;
#pragma unroll
  for (int g = 0; g < 3; ++g) {
    int G = g * 256 + tid;
    int r = G / 24, cx = G - (G / 24) * 24;
    int cb = cx * 8 + 7;
    float a[10], b[10], c[10];
#pragma unroll
    for (int d = 0; d < 10; ++d) {
      a[d] = bf2f(tile[r][cb + d]);
      b[d] = bf2f(tile[r + 1][cb + d]);
      c[d] = bf2f(tile[r + 2][cb + d]);
    }
    bf16x8 ov;
#pragma unroll
    for (int j = 0; j < 8; ++j) {
      float acc = wr[0] * a[j] + wr[1] * a[j + 1] + wr[2] * a[j + 2]
                + wr[3] * b[j] + wr[4] * b[j + 1] + wr[5] * b[j + 2]
                + wr[6] * c[j] + wr[7] * c[j + 1] + wr[8] * c[j + 2];
      ov[j] = f2bf(acc);
    }
    *(bf16x8*)(op + (y0 + r) * WDIM + cx * 8) = ov;
  }
}

// ---------------- scores stage1: partial dots + per-row sumsq chunks ----------------
__global__ __launch_bounds__(256) void scores_stage1(const short* __restrict__ D,
                                                     float* __restrict__ pdot,
                                                     float* __restrict__ qss,
                                                     float* __restrict__ kss) {
  int ch = blockIdx.x, h = blockIdx.y, b = blockIdx.z;
  __shared__ float qs[24][260];
  __shared__ float ks[24][260];
  int tid = threadIdx.x;
  int w = tid >> 6, lane = tid & 63;
  int c0 = w * 6;
  float acc[6] = {0.f, 0.f, 0.f, 0.f, 0.f, 0.f};
  float ssacc = 0.f;
  const short* qb = D + ((size_t)b * OC3 + h * CH) * SSP;
  const short* kb = D + ((size_t)b * OC3 + CDIM + h * CH) * SSP;
  for (int it = 0; it < 8; ++it) {
    int s0 = ch * 2048 + it * 256;
#pragma unroll
    for (int p = 0; p < 3; ++p) {
      int u = p * 256 + tid;
      int row = u >> 5, col8 = u & 31;
      bf16x8 qv = *(const bf16x8*)(qb + (size_t)row * SSP + s0 + col8 * 8);
      bf16x8 kv = *(const bf16x8*)(kb + (size_t)row * SSP + s0 + col8 * 8);
#pragma unroll
      for (int j = 0; j < 8; ++j) {
        qs[row][col8 * 8 + j] = bf2f(qv[j]);
        ks[row][col8 * 8 + j] = bf2f(kv[j]);
      }
    }
    __syncthreads();
    if (w < 2 && lane < 24) {
      const float (*src)[260] = (w == 0) ? qs : ks;
      for (int s = 0; s < 256; s += 4) {
        float4 v = *(const float4*)&src[lane][s];
        ssacc += v.x * v.x + v.y * v.y + v.z * v.z + v.w * v.w;
      }
    }
    if (lane < 24) {
      for (int s = 0; s < 256; s += 4) {
        float4 kv = *(float4*)&ks[lane][s];
#pragma unroll
        for (int i = 0; i < 6; ++i) {
          float4 qv = *(float4*)&qs[c0 + i][s];
          acc[i] += qv.x * kv.x + qv.y * kv.y + qv.z * kv.z + qv.w * kv.w;
        }
      }
    }
    __syncthreads();
  }
  if (lane < 24) {
    float* pb = pdot + (size_t)b * (NHEAD * CH * CH * SCCH);
#pragma unroll
    for (int i = 0; i < 6; ++i)
      pb[(((size_t)h * CH + (c0 + i)) * CH + lane) * SCCH + ch] = acc[i];
    if (w == 0) qss[(((size_t)b * NHEAD + h) * CH + lane) * SCCH + ch] = ssacc;
    if (w == 1) kss[(((size_t)b * NHEAD + h) * CH + lane) * SCCH + ch] = ssacc;
  }
}

// ---------------- scores reduce + norms + temperature + softmax ----------------
__global__ void scores_reduce(const float* __restrict__ pdot,
                              const float* __restrict__ qss,
                              const float* __restrict__ kss,
                              const float* __restrict__ temp,
                              float* __restrict__ atn) {
  int c = blockIdx.x, h = blockIdx.y, b = blockIdx.z;
  int tid = threadIdx.x;   // 64
  __shared__ float row[24];
  if (tid < 24) {
    const float* p = pdot + (size_t)b * (NHEAD * CH * CH * SCCH) +
                     (((size_t)h * CH + c) * CH + tid) * SCCH;
    float s = 0.f;
#pragma unroll
    for (int i = 0; i < SCCH; ++i) s += p[i];
    const float* pq = qss + (((size_t)b * NHEAD + h) * CH + c) * SCCH;
    const float* pk = kss + (((size_t)b * NHEAD + h) * CH + tid) * SCCH;
    float sq = 0.f, sk = 0.f;
#pragma unroll
    for (int i = 0; i < SCCH; ++i) { sq += pq[i]; sk += pk[i]; }
    float rq = 1.f / fmaxf(sqrtf(sq), 1e-12f);
    float rk = 1.f / fmaxf(sqrtf(sk), 1e-12f);
    row[tid] = s * rq * rk * temp[h];
  }
  __syncthreads();
  if (tid < 24) {
    float mx = -1e30f;
    for (int d = 0; d < 24; ++d) mx = fmaxf(mx, row[d]);
    float sum = 0.f;
    for (int d = 0; d < 24; ++d) sum += expf(row[d] - mx);
    atn[((size_t)b * NHEAD + h) * 576 + c * CH + tid] = expf(row[tid] - mx) / sum;
  }
}

// ---------------- PV -> pvt bf16 [b][s][192] ----------------
__global__ __launch_bounds__(256) void attn_pv_bf16(const short* __restrict__ D,
                                                    const float* __restrict__ atn,
                                                    short* __restrict__ pvt) {
  int nb = blockIdx.x, h = blockIdx.y, b = blockIdx.z;
  __shared__ float aL[24][24];
  int tid = threadIdx.x;
  const float* ab = atn + ((size_t)b * NHEAD + h) * 576;
  for (int i = tid; i < 576; i += 256) aL[i / 24][i % 24] = ab[i];
  __syncthreads();
  int n = nb * 256 + tid;
  const short* vb = D + ((size_t)b * OC3 + 2 * CDIM + h * CH) * SSP + n;
  float vv[24];
#pragma unroll
  for (int d = 0; d < 24; ++d) vv[d] = bf2f(vb[(size_t)d * SSP]);
  short* ob = pvt + (size_t)b * SSP * CDIM + (size_t)n * CDIM + h * CH;
  bf16x8 o0, o1, o2;
#pragma unroll
  for (int cc = 0; cc < 24; ++cc) {
    float s = 0.f;
#pragma unroll
    for (int d = 0; d < 24; ++d) s += aL[cc][d] * vv[d];
    short bv = f2bf(s);
    if (cc < 8) o0[cc & 7] = bv; else if (cc < 16) o1[cc & 7] = bv; else o2[cc & 7] = bv;
  }
  *(bf16x8*)(ob) = o0;
  *(bf16x8*)(ob + 8) = o1;
  *(bf16x8*)(ob + 16) = o2;
}

// ---------------- fused MLP v2: LDS-fed, 512 thr, 128-row tile ----------------
// out[m][0..191] += gelu(y2[m][:] @ w1^T + b1) @ w2^T + b2, m-tile = 128 rows.
__global__ __launch_bounds__(512) void mlp_fused(const short* __restrict__ y2,
                                                 const short* __restrict__ w1,
                                                 const short* __restrict__ w2,
                                                 const float* __restrict__ b1,
                                                 const float* __restrict__ b2,
                                                 float* __restrict__ out) {
  __shared__ short y2s[128 * 200];   // 51200 B
  __shared__ short w1s[64 * 200];    // 25600 B
  __shared__ short w2s[192 * 72];    // 27648 B
  __shared__ short h1s[128 * 72];    // 18432 B  (total 120 KiB)
  const int tid = threadIdx.x;
  const int m0 = blockIdx.x * 128;
  const int w = tid >> 6, lane = tid & 63;
  const int r16 = lane & 15, kg = lane >> 4;
  const int wm = w >> 1;   // 0..3 : 32-row band
  const int wn = w & 1;    // 0..1 : hid-half (A) / 96-col half (B)

  // stage y2 tile once: 128 rows x 24 vec8 chunks = 3072 -> 6 per thread
  // (round-6 bug: it<12 overran y2s and raced with w1s staging)
#pragma unroll
  for (int it = 0; it < 6; ++it) {
    int u = it * 512 + tid;            // < 3072
    int row = u / 24, cx = u % 24;
    bf16x8 v = *(const bf16x8*)(y2 + (size_t)(m0 + row) * CDIM + cx * 8);
    *(bf16x8*)(&y2s[row * 200 + cx * 8]) = v;
  }

  f32x4 bacc[2][6] = {};

  for (int hc = 0; hc < 12; ++hc) {
    // stage w1 chunk [64][192] and w2 chunk [192][64]
#pragma unroll
    for (int it = 0; it < 3; ++it) {
      int u = it * 512 + tid;                       // < 1536
      int row = u / 24, cx = u % 24;
      bf16x8 v = *(const bf16x8*)(w1 + (size_t)(hc * 64 + row) * CDIM + cx * 8);
      *(bf16x8*)(&w1s[row * 200 + cx * 8]) = v;
      int row2 = u / 8, cx2 = u % 8;
      bf16x8 v2 = *(const bf16x8*)(w2 + (size_t)row2 * HIDF + hc * 64 + cx2 * 8);
      *(bf16x8*)(&w2s[row2 * 72 + cx2 * 8]) = v2;
    }
    __syncthreads();   // stage visible (also y2s on first iter)

    // phase A: h1c[128][64] = y2s @ w1s^T (K=192); wave: 32 rows x 32 hid
    f32x4 pacc[2][2] = {};
#pragma unroll
    for (int ks = 0; ks < 6; ++ks) {
      bf16x8 af[2], bg[2];
#pragma unroll
      for (int i = 0; i < 2; ++i)
        af[i] = *(bf16x8*)(&y2s[(wm * 32 + i * 16 + r16) * 200 + ks * 32 + kg * 8]);
#pragma unroll
      for (int j = 0; j < 2; ++j)
        bg[j] = *(bf16x8*)(&w1s[(wn * 32 + j * 16 + r16) * 200 + ks * 32 + kg * 8]);
#pragma unroll
      for (int i = 0; i < 2; ++i)
#pragma unroll
        for (int j = 0; j < 2; ++j)
          pacc[i][j] = __builtin_amdgcn_mfma_f32_16x16x32_bf16(af[i], bg[j], pacc[i][j], 0, 0, 0);
    }
    // bias + exact gelu -> h1s bf16
#pragma unroll
    for (int i = 0; i < 2; ++i)
#pragma unroll
      for (int j = 0; j < 2; ++j)
#pragma unroll
        for (int t = 0; t < 4; ++t) {
          int mr = wm * 32 + i * 16 + kg * 4 + t;
          int nc = wn * 32 + j * 16 + r16;
          float v = pacc[i][j][t] + b1[hc * 64 + nc];
          v = 0.5f * v * (1.f + erff(v * 0.70710678118654752f));
          h1s[mr * 72 + nc] = f2bf(v);
        }
    __syncthreads();   // h1s visible

    // phase B: bacc += h1s @ w2s^T (K=64); wave: 32 rows x 96 out-cols
#pragma unroll
    for (int ks = 0; ks < 2; ++ks) {
      bf16x8 a2[2];
#pragma unroll
      for (int i = 0; i < 2; ++i)
        a2[i] = *(bf16x8*)(&h1s[(wm * 32 + i * 16 + r16) * 72 + ks * 32 + kg * 8]);
#pragma unroll
      for (int j = 0; j < 6; ++j) {
        bf16x8 b2g = *(bf16x8*)(&w2s[(wn * 96 + j * 16 + r16) * 72 + ks * 32 + kg * 8]);
#pragma unroll
        for (int i = 0; i < 2; ++i)
          bacc[i][j] = __builtin_amdgcn_mfma_f32_16x16x32_bf16(a2[i], b2g, bacc[i][j], 0, 0, 0);
      }
    }
    __syncthreads();   // reads done before next stage
  }

  // epilogue: out += bacc + b2 (out holds x1 residual)
#pragma unroll
  for (int i = 0; i < 2; ++i)
#pragma unroll
    for (int j = 0; j < 6; ++j)
#pragma unroll
      for (int t = 0; t < 4; ++t) {
        int m = m0 + wm * 32 + i * 16 + kg * 4 + t;
        int n = wn * 96 + j * 16 + r16;
        size_t idx = (size_t)m * CDIM + n;
        out[idx] = bacc[i][j][t] + b2[n] + out[idx];
      }
}

extern "C" void kernel_launch(void* const* d_in, const int* in_sizes, int n_in,
                              void* d_out, int out_size, void* d_ws, size_t ws_size,
                              hipStream_t stream) {
  const float* x      = (const float*)d_in[0];
  const float* ln1_w  = (const float*)d_in[1];
  const float* ln1_b  = (const float*)d_in[2];
  const float* temp   = (const float*)d_in[3];
  const float* qkv_w  = (const float*)d_in[4];
  const float* dw_w   = (const float*)d_in[5];
  const float* proj_w = (const float*)d_in[6];
  const float* ln2_w  = (const float*)d_in[7];
  const float* ln2_b  = (const float*)d_in[8];
  const float* fc1_w  = (const float*)d_in[9];
  const float* fc1_b  = (const float*)d_in[10];
  const float* fc2_w  = (const float*)d_in[11];
  const float* fc2_b  = (const float*)d_in[12];
  float* out = (float*)d_out;

  char* base = (char*)d_ws;
  short* wq  = (short*)base;
  short* wp  = wq + 110592;
  short* w1  = wp + 36864;
  short* w2  = w1 + 147456;
  float* pdot= (float*)(base + 890880);
  float* qss = (float*)(base + 2660352);
  float* kss = (float*)(base + 2734080);
  float* atn = (float*)(base + 2807808);
  short* Dv  = (short*)(base + 4194304);
  short* y1t = Dv;
  short* T   = (short*)(base + 230686720);
  short* pvt = T;
  short* y2  = (short*)(base + 457179136);

  // weights -> bf16
  cvt_bf16<<<dim3(432), 256, 0, stream>>>(qkv_w, wq, 110592);
  cvt_bf16<<<dim3(144), 256, 0, stream>>>(proj_w, wp, 36864);
  cvt_bf16<<<dim3(576), 256, 0, stream>>>(fc1_w, w1, 147456);
  cvt_bf16<<<dim3(576), 256, 0, stream>>>(fc2_w, w2, 147456);

  // 1. LN1 -> y1t bf16 [b][s][192]
  ln_to_bf16T<<<dim3(SSP / 256, NB), 256, 0, stream>>>(x, ln1_w, ln1_b, y1t);
  // 2. qkv GEMM (M=576,N=SSP,K=192, z=4) -> T bf16
  mfma_gemm<64, 256, 1, 4, false, true><<<dim3(SSP / 256, OC3 / 64, NB), 256, 0, stream>>>(
      wq, y1t, nullptr, T, OC3, SSP, CDIM, (long long)SSP * CDIM, (long long)OC3 * SSP);
  // 3. depthwise 3x3 tiled -> Dv bf16
  dwconv_tile<<<dim3(NB * OC3 * 8), 256, 0, stream>>>(T, dw_w, Dv);
  // 4. scores: partial dots + sumsq, then reduce+norm+softmax
  scores_stage1<<<dim3(SCCH, NHEAD, NB), 256, 0, stream>>>(Dv, pdot, qss, kss);
  scores_reduce<<<dim3(CH, NHEAD, NB), 64, 0, stream>>>(pdot, qss, kss, temp, atn);
  // 5. PV -> pvt bf16 [b][s][192]
  attn_pv_bf16<<<dim3(SSP / 256, NHEAD, NB), 256, 0, stream>>>(Dv, atn, pvt);
  // 6. x1 = proj @ pv + x -> out (fp32)
  mfma_gemm<64, 256, 1, 4, true, false><<<dim3(SSP / 256, CDIM / 64, NB), 256, 0, stream>>>(
      wp, pvt, x, out, CDIM, SSP, CDIM, (long long)SSP * CDIM, (long long)CDIM * SSP);
  // 7. LN2 -> y2 bf16 [b][c][s]
  ln_to_bf16N<<<dim3(SSP / 256, NB), 256, 0, stream>>>(out, ln2_w, ln2_b, y2);
  // 8. fused MLP v2: out += gelu(y2@w1^T+b1)@w2^T + b2  (128 rows/block, 512 thr)
  mlp_fused<<<dim3(196608 / 128), 512, 0, stream>>>(y2, w1, w2, fc1_b, fc2_b, out);
}

// Round 8
// 1015.017 us; speedup vs baseline: 3.7680x; 1.0016x over previous
//
#include <hip/hip_runtime.h>
#include <math.h>

// TransformerBlock1: b=4, DIM=192, h=256, w=192, HEADS=8, HID=768
#define SSP   49152
#define HDIM  256
#define WDIM  192
#define CDIM  192
#define NHEAD 8
#define CH    24
#define OC3   576
#define HIDF  768
#define NB    4
#define SCCH  24

typedef short bf16x8 __attribute__((ext_vector_type(8)));
typedef short bf16x4 __attribute__((ext_vector_type(4)));
typedef float f32x4  __attribute__((ext_vector_type(4)));

__device__ inline short f2bf(float f) {
  unsigned u = __float_as_uint(f);
  u += 0x7fffu + ((u >> 16) & 1u);
  return (short)(u >> 16);
}
__device__ inline float bf2f(short h) {
  return __uint_as_float(((unsigned)(unsigned short)h) << 16);
}

// ---------------- f32 -> bf16 bulk convert (weights) ----------------
__global__ __launch_bounds__(256) void cvt_bf16(const float* __restrict__ in,
                                                short* __restrict__ out, int n) {
  int i = blockIdx.x * 256 + threadIdx.x;
  if (i < n) out[i] = f2bf(in[i]);
}

// ---------------- LN(channel) -> bf16 transposed [b][s][192] ----------------
__global__ __launch_bounds__(256) void ln_to_bf16T(const float* __restrict__ x,
                                                   const float* __restrict__ w,
                                                   const float* __restrict__ b,
                                                   short* __restrict__ yt) {
  int s = blockIdx.x * 256 + threadIdx.x;
  int bz = blockIdx.y;
  const float* xb = x + (size_t)bz * CDIM * SSP;
  float sum = 0.f, sq = 0.f;
  for (int c = 0; c < CDIM; ++c) {
    float v = xb[(size_t)c * SSP + s];
    sum += v; sq += v * v;
  }
  float mu = sum * (1.f / CDIM);
  float rstd = rsqrtf(sq * (1.f / CDIM) - mu * mu + 1e-5f);
  short* yp = yt + (size_t)bz * SSP * CDIM + (size_t)s * CDIM;
  for (int c8 = 0; c8 < CDIM / 8; ++c8) {
    bf16x8 v;
#pragma unroll
    for (int j = 0; j < 8; ++j) {
      int c = c8 * 8 + j;
      v[j] = f2bf((xb[(size_t)c * SSP + s] - mu) * rstd * w[c] + b[c]);
    }
    *(bf16x8*)(yp + c8 * 8) = v;
  }
}

// ---------------- LN(channel) -> bf16 natural [b][c][s] ----------------
__global__ __launch_bounds__(256) void ln_to_bf16N(const float* __restrict__ x,
                                                   const float* __restrict__ w,
                                                   const float* __restrict__ b,
                                                   short* __restrict__ y) {
  int s = blockIdx.x * 256 + threadIdx.x;
  int bz = blockIdx.y;
  const float* xb = x + (size_t)bz * CDIM * SSP;
  short* yb = y + (size_t)bz * CDIM * SSP;
  float sum = 0.f, sq = 0.f;
  for (int c = 0; c < CDIM; ++c) {
    float v = xb[(size_t)c * SSP + s];
    sum += v; sq += v * v;
  }
  float mu = sum * (1.f / CDIM);
  float rstd = rsqrtf(sq * (1.f / CDIM) - mu * mu + 1e-5f);
  for (int c = 0; c < CDIM; ++c) {
    float v = xb[(size_t)c * SSP + s];
    yb[(size_t)c * SSP + s] = f2bf((v - mu) * rstd * w[c] + b[c]);
  }
}

// ---------------- MFMA bf16 GEMM NT, batched over z ----------------
template <int BM, int BN, int WM, int WN, bool RESID, bool OUT_BF16>
__global__ __launch_bounds__(256) void mfma_gemm(
    const short* __restrict__ A, const short* __restrict__ B,
    const float* __restrict__ resid, void* __restrict__ Cv,
    int M, int N, int K, long long strideB, long long strideC) {
  constexpr int BK = 32, PAD = 40;
  constexpr int WTM = BM / WM, WTN = BN / WN;
  constexpr int FM = WTM / 16, FN = WTN / 16;
  static_assert(WM * WN == 4 && BM % 64 == 0 && BN % 64 == 0, "cfg");
  __shared__ short As[BM * PAD];
  __shared__ short Bs[BN * PAD];
  const int tid = threadIdx.x;
  const int m0 = blockIdx.y * BM, n0 = blockIdx.x * BN;
  const long long z = blockIdx.z;
  const short* Bz = B + z * strideB;
  const int w = tid >> 6, lane = tid & 63;
  const int wm = w / WN, wn = w % WN;
  const int r16 = lane & 15, kg = lane >> 4;
  const int arow = tid >> 2, akc = tid & 3;

  f32x4 acc[FM][FN] = {};

  for (int k0 = 0; k0 < K; k0 += BK) {
#pragma unroll
    for (int i = 0; i < BM; i += 64) {
      bf16x8 v = *(const bf16x8*)(A + (size_t)(m0 + i + arow) * K + k0 + akc * 8);
      *(bf16x8*)(&As[(i + arow) * PAD + akc * 8]) = v;
    }
#pragma unroll
    for (int i = 0; i < BN; i += 64) {
      bf16x8 v = *(const bf16x8*)(Bz + (size_t)(n0 + i + arow) * K + k0 + akc * 8);
      *(bf16x8*)(&Bs[(i + arow) * PAD + akc * 8]) = v;
    }
    __syncthreads();
    bf16x8 af[FM], bfr[FN];
#pragma unroll
    for (int i = 0; i < FM; ++i)
      af[i] = *(bf16x8*)(&As[(wm * WTM + i * 16 + r16) * PAD + kg * 8]);
#pragma unroll
    for (int j = 0; j < FN; ++j)
      bfr[j] = *(bf16x8*)(&Bs[(wn * WTN + j * 16 + r16) * PAD + kg * 8]);
#pragma unroll
    for (int i = 0; i < FM; ++i)
#pragma unroll
      for (int j = 0; j < FN; ++j)
        acc[i][j] = __builtin_amdgcn_mfma_f32_16x16x32_bf16(af[i], bfr[j], acc[i][j], 0, 0, 0);
    __syncthreads();
  }

  float* Cf = (float*)Cv + z * strideC;
  short* Ch = (short*)Cv + z * strideC;
  const float* R = RESID ? resid + z * strideC : nullptr;
#pragma unroll
  for (int i = 0; i < FM; ++i) {
#pragma unroll
    for (int j = 0; j < FN; ++j) {
#pragma unroll
      for (int t = 0; t < 4; ++t) {
        int m = m0 + wm * WTM + i * 16 + kg * 4 + t;
        int n = n0 + wn * WTN + j * 16 + r16;
        float v = acc[i][j][t];
        size_t idx = (size_t)m * N + n;
        if (RESID) v += R[idx];
        if (OUT_BF16) Ch[idx] = f2bf(v); else Cf[idx] = v;
      }
    }
  }
}

// ---------------- 3x3 depthwise conv, LDS-tiled, bf16->bf16 ----------------
__global__ __launch_bounds__(256) void dwconv_tile(const short* __restrict__ in,
                                                   const float* __restrict__ w9,
                                                   short* __restrict__ out) {
  __shared__ short tile[34][208];
  const int tid = threadIdx.x;
  const int ch = blockIdx.x >> 3;
  const int slab = blockIdx.x & 7;
  const int o = ch % OC3;
  const int y0 = slab * 32;
  float wr[9];
#pragma unroll
  for (int i = 0; i < 9; ++i) wr[i] = w9[o * 9 + i];
  const short* ip = in + (size_t)ch * SSP;

  if (tid < 34) { tile[tid][7] = 0; tile[tid][200] = 0; }
#pragma unroll
  for (int i = 0; i < 4; ++i) {
    int idx = i * 256 + tid;
    if (idx < 816) {
      int row = idx / 24, cx = idx - row * 24;
      int gy = y0 + row - 1;
      bf16x8 v = {};
      if (gy >= 0 && gy < HDIM) v = *(const bf16x8*)(ip + gy * WDIM + cx * 8);
      *(bf16x8*)(&tile[row][8 + cx * 8]) = v;
    }
  }
  __syncthreads();

  short* op = out + (size_t)ch * SSP;
#pragma unroll
  for (int g = 0; g < 3; ++g) {
    int G = g * 256 + tid;
    int r = G / 24, cx = G - (G / 24) * 24;
    int cb = cx * 8 + 7;
    float a[10], b[10], c[10];
#pragma unroll
    for (int d = 0; d < 10; ++d) {
      a[d] = bf2f(tile[r][cb + d]);
      b[d] = bf2f(tile[r + 1][cb + d]);
      c[d] = bf2f(tile[r + 2][cb + d]);
    }
    bf16x8 ov;
#pragma unroll
    for (int j = 0; j < 8; ++j) {
      float acc = wr[0] * a[j] + wr[1] * a[j + 1] + wr[2] * a[j + 2]
                + wr[3] * b[j] + wr[4] * b[j + 1] + wr[5] * b[j + 2]
                + wr[6] * c[j] + wr[7] * c[j + 1] + wr[8] * c[j + 2];
      ov[j] = f2bf(acc);
    }
    *(bf16x8*)(op + (y0 + r) * WDIM + cx * 8) = ov;
  }
}

// ---------------- scores stage1: partial dots + per-row sumsq chunks ----------------
__global__ __launch_bounds__(256) void scores_stage1(const short* __restrict__ D,
                                                     float* __restrict__ pdot,
                                                     float* __restrict__ qss,
                                                     float* __restrict__ kss) {
  int ch = blockIdx.x, h = blockIdx.y, b = blockIdx.z;
  __shared__ float qs[24][260];
  __shared__ float ks[24][260];
  int tid = threadIdx.x;
  int w = tid >> 6, lane = tid & 63;
  int c0 = w * 6;
  float acc[6] = {0.f, 0.f, 0.f, 0.f, 0.f, 0.f};
  float ssacc = 0.f;
  const short* qb = D + ((size_t)b * OC3 + h * CH) * SSP;
  const short* kb = D + ((size_t)b * OC3 + CDIM + h * CH) * SSP;
  for (int it = 0; it < 8; ++it) {
    int s0 = ch * 2048 + it * 256;
#pragma unroll
    for (int p = 0; p < 3; ++p) {
      int u = p * 256 + tid;
      int row = u >> 5, col8 = u & 31;
      bf16x8 qv = *(const bf16x8*)(qb + (size_t)row * SSP + s0 + col8 * 8);
      bf16x8 kv = *(const bf16x8*)(kb + (size_t)row * SSP + s0 + col8 * 8);
#pragma unroll
      for (int j = 0; j < 8; ++j) {
        qs[row][col8 * 8 + j] = bf2f(qv[j]);
        ks[row][col8 * 8 + j] = bf2f(kv[j]);
      }
    }
    __syncthreads();
    if (w < 2 && lane < 24) {
      const float (*src)[260] = (w == 0) ? qs : ks;
      for (int s = 0; s < 256; s += 4) {
        float4 v = *(const float4*)&src[lane][s];
        ssacc += v.x * v.x + v.y * v.y + v.z * v.z + v.w * v.w;
      }
    }
    if (lane < 24) {
      for (int s = 0; s < 256; s += 4) {
        float4 kv = *(float4*)&ks[lane][s];
#pragma unroll
        for (int i = 0; i < 6; ++i) {
          float4 qv = *(float4*)&qs[c0 + i][s];
          acc[i] += qv.x * kv.x + qv.y * kv.y + qv.z * kv.z + qv.w * kv.w;
        }
      }
    }
    __syncthreads();
  }
  if (lane < 24) {
    float* pb = pdot + (size_t)b * (NHEAD * CH * CH * SCCH);
#pragma unroll
    for (int i = 0; i < 6; ++i)
      pb[(((size_t)h * CH + (c0 + i)) * CH + lane) * SCCH + ch] = acc[i];
    if (w == 0) qss[(((size_t)b * NHEAD + h) * CH + lane) * SCCH + ch] = ssacc;
    if (w == 1) kss[(((size_t)b * NHEAD + h) * CH + lane) * SCCH + ch] = ssacc;
  }
}

// ---------------- scores reduce + norms + temperature + softmax ----------------
__global__ void scores_reduce(const float* __restrict__ pdot,
                              const float* __restrict__ qss,
                              const float* __restrict__ kss,
                              const float* __restrict__ temp,
                              float* __restrict__ atn) {
  int c = blockIdx.x, h = blockIdx.y, b = blockIdx.z;
  int tid = threadIdx.x;   // 64
  __shared__ float row[24];
  if (tid < 24) {
    const float* p = pdot + (size_t)b * (NHEAD * CH * CH * SCCH) +
                     (((size_t)h * CH + c) * CH + tid) * SCCH;
    float s = 0.f;
#pragma unroll
    for (int i = 0; i < SCCH; ++i) s += p[i];
    const float* pq = qss + (((size_t)b * NHEAD + h) * CH + c) * SCCH;
    const float* pk = kss + (((size_t)b * NHEAD + h) * CH + tid) * SCCH;
    float sq = 0.f, sk = 0.f;
#pragma unroll
    for (int i = 0; i < SCCH; ++i) { sq += pq[i]; sk += pk[i]; }
    float rq = 1.f / fmaxf(sqrtf(sq), 1e-12f);
    float rk = 1.f / fmaxf(sqrtf(sk), 1e-12f);
    row[tid] = s * rq * rk * temp[h];
  }
  __syncthreads();
  if (tid < 24) {
    float mx = -1e30f;
    for (int d = 0; d < 24; ++d) mx = fmaxf(mx, row[d]);
    float sum = 0.f;
    for (int d = 0; d < 24; ++d) sum += expf(row[d] - mx);
    atn[((size_t)b * NHEAD + h) * 576 + c * CH + tid] = expf(row[tid] - mx) / sum;
  }
}

// ---------------- PV -> pvt bf16 [b][s][192] ----------------
__global__ __launch_bounds__(256) void attn_pv_bf16(const short* __restrict__ D,
                                                    const float* __restrict__ atn,
                                                    short* __restrict__ pvt) {
  int nb = blockIdx.x, h = blockIdx.y, b = blockIdx.z;
  __shared__ float aL[24][24];
  int tid = threadIdx.x;
  const float* ab = atn + ((size_t)b * NHEAD + h) * 576;
  for (int i = tid; i < 576; i += 256) aL[i / 24][i % 24] = ab[i];
  __syncthreads();
  int n = nb * 256 + tid;
  const short* vb = D + ((size_t)b * OC3 + 2 * CDIM + h * CH) * SSP + n;
  float vv[24];
#pragma unroll
  for (int d = 0; d < 24; ++d) vv[d] = bf2f(vb[(size_t)d * SSP]);
  short* ob = pvt + (size_t)b * SSP * CDIM + (size_t)n * CDIM + h * CH;
  bf16x8 o0, o1, o2;
#pragma unroll
  for (int cc = 0; cc < 24; ++cc) {
    float s = 0.f;
#pragma unroll
    for (int d = 0; d < 24; ++d) s += aL[cc][d] * vv[d];
    short bv = f2bf(s);
    if (cc < 8) o0[cc & 7] = bv; else if (cc < 16) o1[cc & 7] = bv; else o2[cc & 7] = bv;
  }
  *(bf16x8*)(ob) = o0;
  *(bf16x8*)(ob + 8) = o1;
  *(bf16x8*)(ob + 16) = o2;
}

// ---------------- fused MLP v3: LDS-fed + swapped phase-A + reg-prefetched weights ----------------
// out[m][0..191] += gelu(y2[m][:] @ w1^T + b1) @ w2^T + b2, m-tile = 128 rows.
__global__ __launch_bounds__(512) void mlp_fused(const short* __restrict__ y2,
                                                 const short* __restrict__ w1,
                                                 const short* __restrict__ w2,
                                                 const float* __restrict__ b1,
                                                 const float* __restrict__ b2,
                                                 float* __restrict__ out) {
  __shared__ short y2s[128 * 200];   // 51200 B
  __shared__ short w1s[64 * 200];    // 25600 B
  __shared__ short w2s[192 * 72];    // 27648 B
  __shared__ short h1s[128 * 72];    // 18432 B  (total 120 KiB)
  const int tid = threadIdx.x;
  const int m0 = blockIdx.x * 128;
  const int w = tid >> 6, lane = tid & 63;
  const int r16 = lane & 15, kg = lane >> 4;
  const int wm = w >> 1;   // 0..3 : 32-row band
  const int wn = w & 1;    // 0..1 : hid-half (A) / 96-col half (B)

  // staging index sets (shared by initial stage, prefetch, and LDS write-back)
  const int u0 = tid, u1 = 512 + tid, u2 = 1024 + tid;   // < 1536
  const int s1r[3] = {u0 / 24, u1 / 24, u2 / 24};        // w1 row 0..63
  const int s1c[3] = {u0 % 24, u1 % 24, u2 % 24};
  const int s2r[3] = {u0 / 8, u1 / 8, u2 / 8};           // w2 row 0..191
  const int s2c[3] = {u0 % 8, u1 % 8, u2 % 8};

  // stage y2 tile once: 128 rows x 24 vec8 chunks = 3072 -> 6 per thread
#pragma unroll
  for (int it = 0; it < 6; ++it) {
    int u = it * 512 + tid;            // < 3072
    int row = u / 24, cx = u % 24;
    bf16x8 v = *(const bf16x8*)(y2 + (size_t)(m0 + row) * CDIM + cx * 8);
    *(bf16x8*)(&y2s[row * 200 + cx * 8]) = v;
  }
  // stage chunk 0 weights direct global->LDS
#pragma unroll
  for (int it = 0; it < 3; ++it) {
    bf16x8 v = *(const bf16x8*)(w1 + (size_t)s1r[it] * CDIM + s1c[it] * 8);
    *(bf16x8*)(&w1s[s1r[it] * 200 + s1c[it] * 8]) = v;
    bf16x8 v2 = *(const bf16x8*)(w2 + (size_t)s2r[it] * HIDF + s2c[it] * 8);
    *(bf16x8*)(&w2s[s2r[it] * 72 + s2c[it] * 8]) = v2;
  }
  __syncthreads();

  f32x4 bacc[2][6] = {};
  bf16x8 rw1[3], rw2[3];

  for (int hc = 0; hc < 12; ++hc) {
    // issue next chunk's weight loads early (latency hides under phases A+B)
    if (hc < 11) {
#pragma unroll
      for (int it = 0; it < 3; ++it) {
        rw1[it] = *(const bf16x8*)(w1 + (size_t)((hc + 1) * 64 + s1r[it]) * CDIM + s1c[it] * 8);
        rw2[it] = *(const bf16x8*)(w2 + (size_t)s2r[it] * HIDF + (hc + 1) * 64 + s2c[it] * 8);
      }
    }

    // phase A (SWAPPED operands): D[hid][m] so acc regs run along hid.
    // pacc[i][j]: m-tile i (m = wm*32+i*16+r16), hid-tile j (hid = wn*32+j*16+kg*4+t)
    f32x4 pacc[2][2] = {};
#pragma unroll
    for (int ks = 0; ks < 6; ++ks) {
      bf16x8 af[2], bg[2];
#pragma unroll
      for (int i = 0; i < 2; ++i)
        af[i] = *(bf16x8*)(&y2s[(wm * 32 + i * 16 + r16) * 200 + ks * 32 + kg * 8]);
#pragma unroll
      for (int j = 0; j < 2; ++j)
        bg[j] = *(bf16x8*)(&w1s[(wn * 32 + j * 16 + r16) * 200 + ks * 32 + kg * 8]);
#pragma unroll
      for (int i = 0; i < 2; ++i)
#pragma unroll
        for (int j = 0; j < 2; ++j)
          pacc[i][j] = __builtin_amdgcn_mfma_f32_16x16x32_bf16(bg[j], af[i], pacc[i][j], 0, 0, 0);
    }
    // bias + exact gelu -> h1s via packed 8B writes (4 consecutive hid per lane)
#pragma unroll
    for (int i = 0; i < 2; ++i) {
      int mr = wm * 32 + i * 16 + r16;
#pragma unroll
      for (int j = 0; j < 2; ++j) {
        int hid0 = wn * 32 + j * 16 + kg * 4;
        bf16x4 pk;
#pragma unroll
        for (int t = 0; t < 4; ++t) {
          float v = pacc[i][j][t] + b1[hc * 64 + hid0 + t];
          v = 0.5f * v * (1.f + erff(v * 0.70710678118654752f));
          pk[t] = f2bf(v);
        }
        *(bf16x4*)(&h1s[mr * 72 + hid0]) = pk;
      }
    }
    __syncthreads();   // h1s visible

    // phase B: bacc += h1s @ w2s^T (K=64); wave: 32 rows x 96 out-cols
#pragma unroll
    for (int ks = 0; ks < 2; ++ks) {
      bf16x8 a2[2];
#pragma unroll
      for (int i = 0; i < 2; ++i)
        a2[i] = *(bf16x8*)(&h1s[(wm * 32 + i * 16 + r16) * 72 + ks * 32 + kg * 8]);
#pragma unroll
      for (int j = 0; j < 6; ++j) {
        bf16x8 b2g = *(bf16x8*)(&w2s[(wn * 96 + j * 16 + r16) * 72 + ks * 32 + kg * 8]);
#pragma unroll
        for (int i = 0; i < 2; ++i)
          bacc[i][j] = __builtin_amdgcn_mfma_f32_16x16x32_bf16(a2[i], b2g, bacc[i][j], 0, 0, 0);
      }
    }
    __syncthreads();   // all reads of w1s/w2s/h1s done

    // write prefetched regs -> LDS for next chunk
    if (hc < 11) {
#pragma unroll
      for (int it = 0; it < 3; ++it) {
        *(bf16x8*)(&w1s[s1r[it] * 200 + s1c[it] * 8]) = rw1[it];
        *(bf16x8*)(&w2s[s2r[it] * 72 + s2c[it] * 8]) = rw2[it];
      }
      __syncthreads();
    }
  }

  // epilogue: out += bacc + b2 (out holds x1 residual)
#pragma unroll
  for (int i = 0; i < 2; ++i)
#pragma unroll
    for (int j = 0; j < 6; ++j)
#pragma unroll
      for (int t = 0; t < 4; ++t) {
        int m = m0 + wm * 32 + i * 16 + kg * 4 + t;
        int n = wn * 96 + j * 16 + r16;
        size_t idx = (size_t)m * CDIM + n;
        out[idx] = bacc[i][j][t] + b2[n] + out[idx];
      }
}

extern "C" void kernel_launch(void* const* d_in, const int* in_sizes, int n_in,
                              void* d_out, int out_size, void* d_ws, size_t ws_size,
                              hipStream_t stream) {
  const float* x      = (const float*)d_in[0];
  const float* ln1_w  = (const float*)d_in[1];
  const float* ln1_b  = (const float*)d_in[2];
  const float* temp   = (const float*)d_in[3];
  const float* qkv_w  = (const float*)d_in[4];
  const float* dw_w   = (const float*)d_in[5];
  const float* proj_w = (const float*)d_in[6];
  const float* ln2_w  = (const float*)d_in[7];
  const float* ln2_b  = (const float*)d_in[8];
  const float* fc1_w  = (const float*)d_in[9];
  const float* fc1_b  = (const float*)d_in[10];
  const float* fc2_w  = (const float*)d_in[11];
  const float* fc2_b  = (const float*)d_in[12];
  float* out = (float*)d_out;

  char* base = (char*)d_ws;
  short* wq  = (short*)base;
  short* wp  = wq + 110592;
  short* w1  = wp + 36864;
  short* w2  = w1 + 147456;
  float* pdot= (float*)(base + 890880);
  float* qss = (float*)(base + 2660352);
  float* kss = (float*)(base + 2734080);
  float* atn = (float*)(base + 2807808);
  short* Dv  = (short*)(base + 4194304);
  short* y1t = Dv;
  short* T   = (short*)(base + 230686720);
  short* pvt = T;
  short* y2  = (short*)(base + 457179136);

  // weights -> bf16
  cvt_bf16<<<dim3(432), 256, 0, stream>>>(qkv_w, wq, 110592);
  cvt_bf16<<<dim3(144), 256, 0, stream>>>(proj_w, wp, 36864);
  cvt_bf16<<<dim3(576), 256, 0, stream>>>(fc1_w, w1, 147456);
  cvt_bf16<<<dim3(576), 256, 0, stream>>>(fc2_w, w2, 147456);

  // 1. LN1 -> y1t bf16 [b][s][192]
  ln_to_bf16T<<<dim3(SSP / 256, NB), 256, 0, stream>>>(x, ln1_w, ln1_b, y1t);
  // 2. qkv GEMM (M=576,N=SSP,K=192, z=4) -> T bf16
  mfma_gemm<64, 256, 1, 4, false, true><<<dim3(SSP / 256, OC3 / 64, NB), 256, 0, stream>>>(
      wq, y1t, nullptr, T, OC3, SSP, CDIM, (long long)SSP * CDIM, (long long)OC3 * SSP);
  // 3. depthwise 3x3 tiled -> Dv bf16
  dwconv_tile<<<dim3(NB * OC3 * 8), 256, 0, stream>>>(T, dw_w, Dv);
  // 4. scores: partial dots + sumsq, then reduce+norm+softmax
  scores_stage1<<<dim3(SCCH, NHEAD, NB), 256, 0, stream>>>(Dv, pdot, qss, kss);
  scores_reduce<<<dim3(CH, NHEAD, NB), 64, 0, stream>>>(pdot, qss, kss, temp, atn);
  // 5. PV -> pvt bf16 [b][s][192]
  attn_pv_bf16<<<dim3(SSP / 256, NHEAD, NB), 256, 0, stream>>>(Dv, atn, pvt);
  // 6. x1 = proj @ pv + x -> out (fp32)
  mfma_gemm<64, 256, 1, 4, true, false><<<dim3(SSP / 256, CDIM / 64, NB), 256, 0, stream>>>(
      wp, pvt, x, out, CDIM, SSP, CDIM, (long long)SSP * CDIM, (long long)CDIM * SSP);
  // 7. LN2 -> y2 bf16 [b][c][s]
  ln_to_bf16N<<<dim3(SSP / 256, NB), 256, 0, stream>>>(out, ln2_w, ln2_b, y2);
  // 8. fused MLP v3
  mlp_fused<<<dim3(196608 / 128), 512, 0, stream>>>(y2, w1, w2, fc1_b, fc2_b, out);
}